// Round 5
// baseline (1014.022 us; speedup 1.0000x reference)
//
#include <hip/hip_runtime.h>

typedef unsigned short u16;
typedef unsigned int u32;
typedef __bf16 bf16x8 __attribute__((ext_vector_type(8)));
typedef float f32x4 __attribute__((ext_vector_type(4)));

// Problem constants
#define NTOK   8192      // B*S
#define DDIM   1024
#define NEXP   8
#define HDIM   1024
#define PAIRS  16384     // NTOK * K

// ---------------- helpers ----------------
__device__ __forceinline__ u16 f2bf(float f) {
  union { float f; u32 u; } v; v.f = f;
  u32 r = v.u + 0x7FFFu + ((v.u >> 16) & 1u);   // RNE
  return (u16)(r >> 16);
}

__device__ __forceinline__ f32x4 mfma16(bf16x8 a, bf16x8 b, f32x4 c) {
  return __builtin_amdgcn_mfma_f32_16x16x32_bf16(a, b, c, 0, 0, 0);
}

// async global->LDS gather DMA, 16B per lane, lds dst = base + lane*16
__device__ __forceinline__ void gload16(const void* g, void* l) {
  __builtin_amdgcn_global_load_lds(
      (__attribute__((address_space(1))) void*)g,
      (__attribute__((address_space(3))) void*)l, 16, 0, 0);
}

// ---------------- prep: router (blocks 0..1023) + weight transposes (1024..17407) ----
// Router: half-wave per token; x read once; emits xb bf16, sel/selw, loss partials.
// Transpose: z<8: w1t[e][h][d]=w1[d][e*1024+h]; z>=8: w2t[e][d][h]=w2[e][h][d].
// Last block (global ticket) computes per-expert prefix offsets.
__global__ __launch_bounds__(256) void prep_kernel(
    const float* __restrict__ x, const float* __restrict__ rw,
    const float* __restrict__ ebias,
    const float* __restrict__ w1, const float* __restrict__ w2,
    u16* __restrict__ xb, u16* __restrict__ w1t, u16* __restrict__ w2t,
    int2* __restrict__ sel, float2* __restrict__ selw,
    u32* __restrict__ cnt, u32* __restrict__ cnt_be,
    float* __restrict__ pe_sum, float* __restrict__ z_sum,
    u32* __restrict__ offs, u32* __restrict__ cursor, u32* __restrict__ ticket) {
  __shared__ float smem[8 * 1028];      // 32.9 KB: router rw_lds / transpose tile
  __shared__ float pe_loc[8];
  __shared__ float z_loc;
  __shared__ u32 cl[8];
  int tid = threadIdx.x;

  if (blockIdx.x < 1024) {
    // ---------- router ----------
    for (int i = tid; i < 8192; i += 256)
      smem[(i >> 10) * 1028 + (i & 1023)] = rw[i];
    if (tid < 8) { pe_loc[tid] = 0.f; cl[tid] = 0u; }
    if (tid == 8) z_loc = 0.f;
    __syncthreads();

    int ht = tid >> 5;          // half-wave id 0..7 -> token slot
    int hl = tid & 31;
    int t = blockIdx.x * 8 + ht;
    const float* xr = x + (long)t * DDIM;
    u16* xbr = xb + (long)t * DDIM;
    double acc[8];
    #pragma unroll
    for (int e = 0; e < 8; e++) acc[e] = 0.0;
    #pragma unroll
    for (int p = 0; p < 8; p++) {
      int d = p * 128 + hl * 4;
      float4 xv = *(const float4*)(xr + d);
      *(ushort4*)(xbr + d) = make_ushort4(f2bf(xv.x), f2bf(xv.y), f2bf(xv.z), f2bf(xv.w));
      #pragma unroll
      for (int e = 0; e < 8; e++) {
        float4 wv = *(const float4*)(smem + e * 1028 + d);
        acc[e] += (double)xv.x * (double)wv.x + (double)xv.y * (double)wv.y
                + (double)xv.z * (double)wv.z + (double)xv.w * (double)wv.w;
      }
    }
    #pragma unroll
    for (int e = 0; e < 8; e++) {
      #pragma unroll
      for (int off = 16; off > 0; off >>= 1)
        acc[e] += __shfl_down(acc[e], off, 32);
    }
    if (hl == 0) {
      double logit[8]; float p8[8], score[8];
      for (int e = 0; e < 8; e++) {
        logit[e] = acc[e];
        p8[e] = (float)(1.0 / (1.0 + exp(-logit[e])));
        score[e] = p8[e] + ebias[e];
      }
      // top-2, ties -> lowest index (lax.top_k is stable)
      int i0 = 0;
      for (int e = 1; e < 8; e++) if (score[e] > score[i0]) i0 = e;
      int i1 = (i0 == 0) ? 1 : 0;
      for (int e = 0; e < 8; e++) if (e != i0 && score[e] > score[i1]) i1 = e;
      float w0 = p8[i0], w1v = p8[i1];
      float ssum = w0 + w1v + 1e-20f;
      sel[t] = make_int2(i0, i1);
      selw[t] = make_float2(w0 / ssum, w1v / ssum);
      double m = logit[0];
      for (int e = 1; e < 8; e++) m = fmax(m, logit[e]);
      double se = 0.0;
      for (int e = 0; e < 8; e++) se += exp(logit[e] - m);
      double ls = m + log(se);
      atomicAdd(&z_loc, (float)(ls * ls));
      for (int e = 0; e < 8; e++) atomicAdd(&pe_loc[e], p8[e]);
      atomicAdd(&cl[i0], 1u); atomicAdd(&cl[i1], 1u);
    }
    __syncthreads();
    if (tid < 8) {
      int b = (int)((blockIdx.x * 8) >> 11);   // S = 2048, uniform per block
      atomicAdd(&cnt[tid], cl[tid]);
      atomicAdd(&cnt_be[b * 8 + tid], cl[tid]);
      atomicAdd(&pe_sum[b * 8 + tid], pe_loc[tid]);
    }
    if (tid == 8) atomicAdd(z_sum, z_loc);
  } else {
    // ---------- transpose+cast ----------
    float (*tile)[33] = (float(*)[33])smem;
    int bid = blockIdx.x - 1024;
    int z = bid >> 10;
    int by = (bid >> 5) & 31, bx = bid & 31;
    const float* ib; long rs; u16* ob;
    if (z < 8) { ib = w1 + z * 1024; rs = 8192; ob = w1t + (long)z * 1048576; }
    else       { ib = w2 + (long)(z - 8) * 1048576; rs = 1024; ob = w2t + (long)(z - 8) * 1048576; }
    int r0 = by * 32, c0 = bx * 32;
    int tx = tid & 31, ty = tid >> 5;   // ty in [0,8)
    #pragma unroll
    for (int rr = 0; rr < 32; rr += 8)
      tile[ty + rr][tx] = ib[(long)(r0 + ty + rr) * rs + c0 + tx];
    __syncthreads();
    #pragma unroll
    for (int rr = 0; rr < 32; rr += 8)
      ob[(long)(c0 + ty + rr) * 1024 + r0 + tx] = f2bf(tile[tx][ty + rr]);
  }

  // ---------- last-block: prefix offsets ----------
  __syncthreads();
  if (tid == 0) {
    __threadfence();
    u32 tk = atomicAdd(ticket, 1u);
    if (tk == gridDim.x - 1) {
      u32 a = 0;
      for (int e = 0; e < 8; e++) {
        u32 c = atomicAdd(&cnt[e], 0u);   // atomic read (L2-coherent)
        offs[e] = a; cursor[e] = a; a += c;
      }
    }
  }
}

// ---------------- build expert-sorted pair lists + inverse map + finalize losses ----
__global__ __launch_bounds__(256) void build_finalize(
    const int2* __restrict__ sel, const float2* __restrict__ selw,
    u32* __restrict__ cursor, int* __restrict__ tok_list, float* __restrict__ wt_list,
    int* __restrict__ inv,
    const float* __restrict__ pe_sum, const float* __restrict__ z_sum,
    const u32* __restrict__ cnt, const u32* __restrict__ cnt_be,
    float* __restrict__ out_tail) {
  int t = blockIdx.x * 256 + threadIdx.x;   // 8192 tokens
  int2 s = sel[t]; float2 w = selw[t];
  u32 p0 = atomicAdd(&cursor[s.x], 1u);
  tok_list[p0] = t; wt_list[p0] = w.x; inv[2 * t] = (int)p0;
  u32 p1 = atomicAdd(&cursor[s.y], 1u);
  tok_list[p1] = t; wt_list[p1] = w.y; inv[2 * t + 1] = (int)p1;

  if (blockIdx.x == 0 && threadIdx.x == 0) {
    float z = z_sum[0] / (float)NTOK;
    float lb = 0.f, clv = 0.f;
    for (int p = 0; p < 32; p++) {
      float psum = pe_sum[p];
      clv += psum;
      float f = (float)cnt_be[p] / 4096.0f;     // S*K
      lb += f * (psum / 2048.0f);               // p_seq mean over S
    }
    lb = 8.0f * lb / 4.0f;                      // E * mean over B
    clv = clv / (float)NTOK;
    out_tail[0] = z;
    out_tail[1] = lb;
    out_tail[2] = clv;
    for (int e2 = 0; e2 < 8; e2++) out_tail[3 + e2] = (float)cnt[e2] / 16384.0f;
  }
}

// ---------------- grouped GEMM: 128x128x64 tiles, DOUBLE-BUFFERED DMA ----------------
// XCD-aware tile map: idx = q8 + 8*(tml*8 + tn), tm = q8*17 + tml. With round-robin
// XCD dispatch (XCD = idx%8 = q8) each XCD owns a CONTIGUOUS row-tile range:
// A slab fetched once per XCD (~4.25 MB), B slabs ~2 experts per XCD.
// SECOND=false: h[slot][n] = relu(x[tok] @ w1t_e[n])^2      (A gathered via tok_list)
// SECOND=true : y[slot][n] = wt[slot] * (h[slot] @ w2t_e[n])
template <bool SECOND>
__global__ __launch_bounds__(256, 2) void moe_gemm(
    const u16* __restrict__ A, const u16* __restrict__ Bt,
    u16* __restrict__ out16,
    const int* __restrict__ tok_list, const float* __restrict__ wt_list,
    const u32* __restrict__ cnt, const u32* __restrict__ offs) {
  int q8 = blockIdx.x & 7;
  int r  = blockIdx.x >> 3;        // 0..135
  int tn = r & 7;
  int tm = q8 * 17 + (r >> 3);     // contiguous 17-row-tile group per XCD
  int e = 0, acct = 0;
  while (e < 8) {
    int nt = (int)((cnt[e] + 127u) >> 7);
    if (tm < acct + nt) break;
    acct += nt; e++;
  }
  if (e == 8) return;              // uniform across block
  int m0 = (tm - acct) * 128;
  int off = (int)offs[e];
  int ce  = (int)cnt[e];

  __shared__ uint4 smem[4096];     // 64 KB: A0[0..1023] A1[1024..2047] B0[2048..] B1[3072..]

  int tid = threadIdx.x;
  int l = tid & 63, w = tid >> 6;

  // staging pointers: lane-linear. slot p = w*256 + j*64 + l -> row=p>>3, c=p&7
  const u16* agp[4]; const u16* bgp[4];
  #pragma unroll
  for (int j = 0; j < 4; j++) {
    int p = w * 256 + j * 64 + l;
    int row = p >> 3, c = p & 7;
    long arow;
    if (SECOND) {
      arow = (long)(off + m0 + row);
    } else {
      int rr = m0 + row; if (rr > ce - 1) rr = ce - 1;   // clamp padded rows
      arow = (long)tok_list[off + rr];
    }
    agp[j] = A + arow * 1024 + c * 8;
    bgp[j] = Bt + (long)e * 1048576 + (long)(tn * 128 + row) * 1024 + c * 8;
  }

  // prologue: DMA tile 0 into buffer 0
  #pragma unroll
  for (int j = 0; j < 4; j++) {
    gload16(agp[j], &smem[w * 256 + j * 64]);
    gload16(bgp[j], &smem[2048 + w * 256 + j * 64]);
    agp[j] += 64; bgp[j] += 64;
  }
  __syncthreads();

  f32x4 acc[4][4];
  #pragma unroll
  for (int i = 0; i < 4; i++)
    #pragma unroll
    for (int j = 0; j < 4; j++) acc[i][j] = (f32x4){0.f, 0.f, 0.f, 0.f};

  int mr = l & 15, q = l >> 4;
  int wm = (w >> 1) * 64, wn = (w & 1) * 64;

  for (int k = 0; k < 16; k++) {
    int cur = k & 1, nxt = cur ^ 1;
    if (k < 15) {
      #pragma unroll
      for (int j = 0; j < 4; j++) {
        gload16(agp[j], &smem[nxt * 1024 + w * 256 + j * 64]);
        gload16(bgp[j], &smem[2048 + nxt * 1024 + w * 256 + j * 64]);
        agp[j] += 64; bgp[j] += 64;
      }
    }
    const uint4* Ab = smem + cur * 1024;
    const uint4* Bb = smem + 2048 + cur * 1024;
    #pragma unroll
    for (int kk = 0; kk < 2; kk++) {
      int cg = kk * 4 + q;
      bf16x8 af[4], bfr[4];
      #pragma unroll
      for (int i = 0; i < 4; i++) {
        af[i]  = __builtin_bit_cast(bf16x8, Ab[(wm + i * 16 + mr) * 8 + cg]);
        bfr[i] = __builtin_bit_cast(bf16x8, Bb[(wn + i * 16 + mr) * 8 + cg]);
      }
      #pragma unroll
      for (int i = 0; i < 4; i++)
        #pragma unroll
        for (int j = 0; j < 4; j++)
          acc[i][j] = mfma16(af[i], bfr[j], acc[i][j]);
    }
    __syncthreads();   // drains this iter's DMA (issued a whole compute phase ago)
  }

  // epilogue: repack wave's 64x64 bf16 tile via LDS (stride 72 u16 = 144B),
  // then 128B-coalesced global stores.
  // C/D layout col=lane&15, row=(lane>>4)*4+reg  [m89-verified]
  u16* ost = (u16*)smem + w * 4608;     // 64 x 72 u16 = 9216 B per wave
  #pragma unroll
  for (int i = 0; i < 4; i++) {
    #pragma unroll
    for (int rr = 0; rr < 4; rr++) {
      int rl = i * 16 + q * 4 + rr;
      float wgt = 1.f;
      if (SECOND) {
        int gr = m0 + wm + rl;
        int slot = (gr < ce) ? (off + gr) : 0;
        wgt = wt_list[slot];
      }
      #pragma unroll
      for (int j = 0; j < 4; j++) {
        float v = acc[i][j][rr];
        if (!SECOND) { v = fmaxf(v, 0.f); v = v * v; }
        else v *= wgt;
        ost[rl * 72 + j * 16 + mr] = f2bf(v);
      }
    }
  }
  // readback: same wave only -> lgkmcnt handles ordering, no barrier needed
  #pragma unroll
  for (int pr = 0; pr < 8; pr++) {
    int rl = pr * 8 + (l >> 3);
    int c8 = l & 7;
    uint4 v = *(const uint4*)(ost + rl * 72 + c8 * 8);
    int gr = m0 + wm + rl;
    if (gr < ce)
      *(uint4*)(out16 + (long)(off + gr) * 1024 + tn * 128 + wn + c8 * 8) = v;
  }
}

// ---------------- combine: out[t] = y[slot0] + y[slot1], 2 tokens/block ----------------
__global__ __launch_bounds__(256) void combine_kernel(
    const u16* __restrict__ y, const int* __restrict__ inv,
    float* __restrict__ out) {
  int t = blockIdx.x * 2 + (threadIdx.x >> 7);
  int tid = threadIdx.x & 127;
  int s0 = inv[2 * t], s1 = inv[2 * t + 1];
  uint4 a = *(const uint4*)(y + (long)s0 * 1024 + tid * 8);
  uint4 b = *(const uint4*)(y + (long)s1 * 1024 + tid * 8);
  float o[8];
  const u32* au = (const u32*)&a;
  const u32* bu = (const u32*)&b;
  #pragma unroll
  for (int i = 0; i < 4; i++) {
    union { u32 u; float f; } lo1, hi1, lo2, hi2;
    lo1.u = au[i] << 16;  hi1.u = au[i] & 0xFFFF0000u;
    lo2.u = bu[i] << 16;  hi2.u = bu[i] & 0xFFFF0000u;
    o[2 * i]     = lo1.f + lo2.f;
    o[2 * i + 1] = hi1.f + hi2.f;
  }
  float* op = out + (long)t * 1024 + tid * 8;
  *(float4*)op       = make_float4(o[0], o[1], o[2], o[3]);
  *(float4*)(op + 4) = make_float4(o[4], o[5], o[6], o[7]);
}

// ---------------- launch ----------------
extern "C" void kernel_launch(void* const* d_in, const int* in_sizes, int n_in,
                              void* d_out, int out_size, void* d_ws, size_t ws_size,
                              hipStream_t stream) {
  const float* x     = (const float*)d_in[0];
  const float* rw    = (const float*)d_in[1];
  const float* w1    = (const float*)d_in[2];
  const float* w2    = (const float*)d_in[3];
  const float* ebias = (const float*)d_in[4];
  float* out = (float*)d_out;

  char* ws = (char*)d_ws;
  // ws layout (bytes). y (GEMM2 output) OVERLAYS xb+w1t (dead after GEMM1).
  u16*    xb        = (u16*)(ws + 0);                 // 16,777,216
  u16*    w1t       = (u16*)(ws + 16777216);          // 16,777,216
  u16*    y         = (u16*)(ws + 0);                 // overlay, 33,554,432
  u16*    w2t       = (u16*)(ws + 33554432);          // 16,777,216
  u16*    h         = (u16*)(ws + 50331648);          // 16512 rows: 33,816,576
  int*    tok_list  = (int*)(ws + 84148224);          // 65,536
  float*  wt_list   = (float*)(ws + 84213760);        // 65,536
  int2*   sel       = (int2*)(ws + 84279296);         // 65,536
  float2* selw      = (float2*)(ws + 84344832);       // 65,536
  int*    inv       = (int*)(ws + 84705280);          // 65,536
  u32*    cnt       = (u32*)(ws + 84770816);          // counters block (512 B, memset 0)
  u32*    cursor    = cnt + 8;
  u32*    cnt_be    = cnt + 16;   // 32 entries [B][E]
  u32*    offs      = cnt + 48;
  float*  pe_sum    = (float*)(cnt + 56);             // 32 floats
  float*  z_sum     = (float*)(cnt + 88);             // 1 float
  u32*    ticket    = cnt + 96;

  hipMemsetAsync(cnt, 0, 512, stream);

  prep_kernel<<<1024 + 16384, 256, 0, stream>>>(
      x, rw, ebias, w1, w2, xb, w1t, w2t, sel, selw,
      cnt, cnt_be, pe_sum, z_sum, offs, cursor, ticket);
  build_finalize<<<32, 256, 0, stream>>>(sel, selw, cursor, tok_list, wt_list, inv,
                                         pe_sum, z_sum, cnt, cnt_be, out + 8388608);
  // worst case sum(ceil(cnt_e/128)) <= 135 row tiles; 8 col tiles; XCD-mapped
  moe_gemm<false><<<136 * 8, 256, 0, stream>>>(xb, w1t, h, tok_list, wt_list, cnt, offs);
  moe_gemm<true><<<136 * 8, 256, 0, stream>>>(h, w2t, y, tok_list, wt_list, cnt, offs);
  combine_kernel<<<4096, 256, 0, stream>>>(y, inv, out);
}

// Round 6
// 369.543 us; speedup vs baseline: 2.7440x; 2.7440x over previous
//
#include <hip/hip_runtime.h>

typedef unsigned short u16;
typedef unsigned int u32;
typedef __bf16 bf16x8 __attribute__((ext_vector_type(8)));
typedef float f32x4 __attribute__((ext_vector_type(4)));

// Problem constants
#define NTOK   8192      // B*S
#define DDIM   1024
#define NEXP   8
#define HDIM   1024
#define PAIRS  16384     // NTOK * K

// ---------------- helpers ----------------
__device__ __forceinline__ u16 f2bf(float f) {
  union { float f; u32 u; } v; v.f = f;
  u32 r = v.u + 0x7FFFu + ((v.u >> 16) & 1u);   // RNE
  return (u16)(r >> 16);
}

__device__ __forceinline__ f32x4 mfma16(bf16x8 a, bf16x8 b, f32x4 c) {
  return __builtin_amdgcn_mfma_f32_16x16x32_bf16(a, b, c, 0, 0, 0);
}

// async global->LDS gather DMA, 16B per lane, lds dst = base + lane*16
__device__ __forceinline__ void gload16(const void* g, void* l) {
  __builtin_amdgcn_global_load_lds(
      (__attribute__((address_space(1))) void*)g,
      (__attribute__((address_space(3))) void*)l, 16, 0, 0);
}

// ---------------- merged transpose+cast of w1 and w2 ----------------
// z<8 : w1t[e][h][d] = w1[d][e*1024+h]   (e = z)
// z>=8: w2t[e][d][h] = w2[e][h][d]       (e = z-8)
__global__ __launch_bounds__(256) void transpose_all(
    const float* __restrict__ w1, const float* __restrict__ w2,
    u16* __restrict__ w1t, u16* __restrict__ w2t) {
  __shared__ float tile[32][33];
  int z = blockIdx.z;
  const float* ib; long rs; u16* ob;
  if (z < 8) { ib = w1 + z * 1024; rs = 8192; ob = w1t + (long)z * 1048576; }
  else       { ib = w2 + (long)(z - 8) * 1048576; rs = 1024; ob = w2t + (long)(z - 8) * 1048576; }
  int r0 = blockIdx.y * 32, c0 = blockIdx.x * 32;
  int tx = threadIdx.x & 31, ty = threadIdx.x >> 5;   // ty in [0,8)
  #pragma unroll
  for (int rr = 0; rr < 32; rr += 8)
    tile[ty + rr][tx] = ib[(long)(r0 + ty + rr) * rs + c0 + tx];
  __syncthreads();
  #pragma unroll
  for (int rr = 0; rr < 32; rr += 8)
    ob[(long)(c0 + ty + rr) * 1024 + r0 + tx] = f2bf(tile[tx][ty + rr]);
}

// ---------------- router: half-wave (32 lanes) per token ----------------
// x read ONCE per token; emits xb (bf16), sel/selw, and loss partials
// (pe_sum[b*8+e], z_sum) via atomics.
__global__ __launch_bounds__(256) void router_kernel(
    const float* __restrict__ x, const float* __restrict__ rw,
    const float* __restrict__ ebias, u16* __restrict__ xb,
    int2* __restrict__ sel, float2* __restrict__ selw,
    u32* __restrict__ cnt, u32* __restrict__ cnt_be,
    float* __restrict__ pe_sum, float* __restrict__ z_sum) {
  __shared__ float rw_lds[8 * 1028];    // +4 pad per row
  __shared__ float pe_loc[8];
  __shared__ float z_loc;
  __shared__ u32 cl[8];
  int tid = threadIdx.x;
  for (int i = tid; i < 8192; i += 256)
    rw_lds[(i >> 10) * 1028 + (i & 1023)] = rw[i];
  if (tid < 8) { pe_loc[tid] = 0.f; cl[tid] = 0u; }
  if (tid == 8) z_loc = 0.f;
  __syncthreads();

  int ht = tid >> 5;          // half-wave id 0..7 -> token slot
  int hl = tid & 31;
  int t = blockIdx.x * 8 + ht;
  const float* xr = x + (long)t * DDIM;
  u16* xbr = xb + (long)t * DDIM;
  double acc[8];
  #pragma unroll
  for (int e = 0; e < 8; e++) acc[e] = 0.0;
  #pragma unroll
  for (int p = 0; p < 8; p++) {
    int d = p * 128 + hl * 4;
    float4 xv = *(const float4*)(xr + d);
    *(ushort4*)(xbr + d) = make_ushort4(f2bf(xv.x), f2bf(xv.y), f2bf(xv.z), f2bf(xv.w));
    #pragma unroll
    for (int e = 0; e < 8; e++) {
      float4 wv = *(const float4*)(rw_lds + e * 1028 + d);
      acc[e] += (double)xv.x * (double)wv.x + (double)xv.y * (double)wv.y
              + (double)xv.z * (double)wv.z + (double)xv.w * (double)wv.w;
    }
  }
  #pragma unroll
  for (int e = 0; e < 8; e++) {
    #pragma unroll
    for (int off = 16; off > 0; off >>= 1)
      acc[e] += __shfl_down(acc[e], off, 32);
  }
  if (hl == 0) {
    double logit[8]; float p8[8], score[8];
    for (int e = 0; e < 8; e++) {
      logit[e] = acc[e];
      p8[e] = (float)(1.0 / (1.0 + exp(-logit[e])));
      score[e] = p8[e] + ebias[e];
    }
    // top-2, ties -> lowest index (lax.top_k is stable)
    int i0 = 0;
    for (int e = 1; e < 8; e++) if (score[e] > score[i0]) i0 = e;
    int i1 = (i0 == 0) ? 1 : 0;
    for (int e = 0; e < 8; e++) if (e != i0 && score[e] > score[i1]) i1 = e;
    float w0 = p8[i0], w1v = p8[i1];
    float ssum = w0 + w1v + 1e-20f;
    sel[t] = make_int2(i0, i1);
    selw[t] = make_float2(w0 / ssum, w1v / ssum);
    double m = logit[0];
    for (int e = 1; e < 8; e++) m = fmax(m, logit[e]);
    double se = 0.0;
    for (int e = 0; e < 8; e++) se += exp(logit[e] - m);
    double ls = m + log(se);
    atomicAdd(&z_loc, (float)(ls * ls));
    for (int e = 0; e < 8; e++) atomicAdd(&pe_loc[e], p8[e]);
    atomicAdd(&cl[i0], 1u); atomicAdd(&cl[i1], 1u);
  }
  __syncthreads();
  if (tid < 8) {
    int b = (int)((blockIdx.x * 8) >> 11);   // S = 2048, uniform per block
    atomicAdd(&cnt[tid], cl[tid]);
    atomicAdd(&cnt_be[b * 8 + tid], cl[tid]);
    atomicAdd(&pe_sum[b * 8 + tid], pe_loc[tid]);
  }
  if (tid == 8) atomicAdd(z_sum, z_loc);
}

// ---------------- prefix offsets (E=8) ----------------
__global__ void offsets_kernel(const u32* __restrict__ cnt, u32* __restrict__ offs,
                               u32* __restrict__ cursor) {
  if (threadIdx.x == 0 && blockIdx.x == 0) {
    u32 a = 0;
    for (int e = 0; e < 8; e++) { offs[e] = a; cursor[e] = a; a += cnt[e]; }
  }
}

// ---------------- build expert-sorted pair lists + inverse map + finalize losses ----
__global__ __launch_bounds__(256) void build_finalize(
    const int2* __restrict__ sel, const float2* __restrict__ selw,
    u32* __restrict__ cursor, int* __restrict__ tok_list, float* __restrict__ wt_list,
    int* __restrict__ inv,
    const float* __restrict__ pe_sum, const float* __restrict__ z_sum,
    const u32* __restrict__ cnt, const u32* __restrict__ cnt_be,
    float* __restrict__ out_tail) {
  int t = blockIdx.x * 256 + threadIdx.x;   // 8192 tokens
  int2 s = sel[t]; float2 w = selw[t];
  u32 p0 = atomicAdd(&cursor[s.x], 1u);
  tok_list[p0] = t; wt_list[p0] = w.x; inv[2 * t] = (int)p0;
  u32 p1 = atomicAdd(&cursor[s.y], 1u);
  tok_list[p1] = t; wt_list[p1] = w.y; inv[2 * t + 1] = (int)p1;

  if (blockIdx.x == 0 && threadIdx.x == 0) {
    float z = z_sum[0] / (float)NTOK;
    float lb = 0.f, clv = 0.f;
    for (int p = 0; p < 32; p++) {
      float psum = pe_sum[p];
      clv += psum;
      float f = (float)cnt_be[p] / 4096.0f;     // S*K
      lb += f * (psum / 2048.0f);               // p_seq mean over S
    }
    lb = 8.0f * lb / 4.0f;                      // E * mean over B
    clv = clv / (float)NTOK;
    out_tail[0] = z;
    out_tail[1] = lb;
    out_tail[2] = clv;
    for (int e2 = 0; e2 < 8; e2++) out_tail[3 + e2] = (float)cnt[e2] / 16384.0f;
  }
}

// ---------------- grouped GEMM: 128x128x64 tiles, DOUBLE-BUFFERED DMA ----------------
// XCD-aware tile map: idx = q8 + 8*(tml*8 + tn), tm = q8*17 + tml. With round-robin
// XCD dispatch (XCD = idx%8 = q8) each XCD owns a CONTIGUOUS row-tile range:
// A slab fetched once per XCD (~4.25 MB), B slabs ~2 experts per XCD.
// SECOND=false: h[slot][n] = relu(x[tok] @ w1t_e[n])^2      (A gathered via tok_list)
// SECOND=true : y[slot][n] = wt[slot] * (h[slot] @ w2t_e[n])
template <bool SECOND>
__global__ __launch_bounds__(256, 2) void moe_gemm(
    const u16* __restrict__ A, const u16* __restrict__ Bt,
    u16* __restrict__ out16,
    const int* __restrict__ tok_list, const float* __restrict__ wt_list,
    const u32* __restrict__ cnt, const u32* __restrict__ offs) {
  int q8 = blockIdx.x & 7;
  int r  = blockIdx.x >> 3;        // 0..135
  int tn = r & 7;
  int tm = q8 * 17 + (r >> 3);     // contiguous 17-row-tile group per XCD
  int e = 0, acct = 0;
  while (e < 8) {
    int nt = (int)((cnt[e] + 127u) >> 7);
    if (tm < acct + nt) break;
    acct += nt; e++;
  }
  if (e == 8) return;              // uniform across block
  int m0 = (tm - acct) * 128;
  int off = (int)offs[e];
  int ce  = (int)cnt[e];

  __shared__ uint4 smem[4096];     // 64 KB: A0[0..1023] A1[1024..2047] B0[2048..] B1[3072..]

  int tid = threadIdx.x;
  int l = tid & 63, w = tid >> 6;

  // staging pointers: lane-linear. slot p = w*256 + j*64 + l -> row=p>>3, c=p&7
  const u16* agp[4]; const u16* bgp[4];
  #pragma unroll
  for (int j = 0; j < 4; j++) {
    int p = w * 256 + j * 64 + l;
    int row = p >> 3, c = p & 7;
    long arow;
    if (SECOND) {
      arow = (long)(off + m0 + row);
    } else {
      int rr = m0 + row; if (rr > ce - 1) rr = ce - 1;   // clamp padded rows
      arow = (long)tok_list[off + rr];
    }
    agp[j] = A + arow * 1024 + c * 8;
    bgp[j] = Bt + (long)e * 1048576 + (long)(tn * 128 + row) * 1024 + c * 8;
  }

  // prologue: DMA tile 0 into buffer 0
  #pragma unroll
  for (int j = 0; j < 4; j++) {
    gload16(agp[j], &smem[w * 256 + j * 64]);
    gload16(bgp[j], &smem[2048 + w * 256 + j * 64]);
    agp[j] += 64; bgp[j] += 64;
  }
  __syncthreads();

  f32x4 acc[4][4];
  #pragma unroll
  for (int i = 0; i < 4; i++)
    #pragma unroll
    for (int j = 0; j < 4; j++) acc[i][j] = (f32x4){0.f, 0.f, 0.f, 0.f};

  int mr = l & 15, q = l >> 4;
  int wm = (w >> 1) * 64, wn = (w & 1) * 64;

  for (int k = 0; k < 16; k++) {
    int cur = k & 1, nxt = cur ^ 1;
    if (k < 15) {
      #pragma unroll
      for (int j = 0; j < 4; j++) {
        gload16(agp[j], &smem[nxt * 1024 + w * 256 + j * 64]);
        gload16(bgp[j], &smem[2048 + nxt * 1024 + w * 256 + j * 64]);
        agp[j] += 64; bgp[j] += 64;
      }
    }
    const uint4* Ab = smem + cur * 1024;
    const uint4* Bb = smem + 2048 + cur * 1024;
    #pragma unroll
    for (int kk = 0; kk < 2; kk++) {
      int cg = kk * 4 + q;
      bf16x8 af[4], bfr[4];
      #pragma unroll
      for (int i = 0; i < 4; i++) {
        af[i]  = __builtin_bit_cast(bf16x8, Ab[(wm + i * 16 + mr) * 8 + cg]);
        bfr[i] = __builtin_bit_cast(bf16x8, Bb[(wn + i * 16 + mr) * 8 + cg]);
      }
      #pragma unroll
      for (int i = 0; i < 4; i++)
        #pragma unroll
        for (int j = 0; j < 4; j++)
          acc[i][j] = mfma16(af[i], bfr[j], acc[i][j]);
    }
    __syncthreads();   // drains this iter's DMA (issued a whole compute phase ago)
  }

  // epilogue: repack wave's 64x64 bf16 tile via LDS (stride 72 u16 = 144B),
  // then 128B-coalesced global stores.
  // C/D layout col=lane&15, row=(lane>>4)*4+reg  [m89-verified]
  u16* ost = (u16*)smem + w * 4608;     // 64 x 72 u16 = 9216 B per wave
  #pragma unroll
  for (int i = 0; i < 4; i++) {
    #pragma unroll
    for (int rr = 0; rr < 4; rr++) {
      int rl = i * 16 + q * 4 + rr;
      float wgt = 1.f;
      if (SECOND) {
        int gr = m0 + wm + rl;
        int slot = (gr < ce) ? (off + gr) : 0;
        wgt = wt_list[slot];
      }
      #pragma unroll
      for (int j = 0; j < 4; j++) {
        float v = acc[i][j][rr];
        if (!SECOND) { v = fmaxf(v, 0.f); v = v * v; }
        else v *= wgt;
        ost[rl * 72 + j * 16 + mr] = f2bf(v);
      }
    }
  }
  // readback: same wave only -> lgkmcnt handles ordering, no barrier needed
  #pragma unroll
  for (int pr = 0; pr < 8; pr++) {
    int rl = pr * 8 + (l >> 3);
    int c8 = l & 7;
    uint4 v = *(const uint4*)(ost + rl * 72 + c8 * 8);
    int gr = m0 + wm + rl;
    if (gr < ce)
      *(uint4*)(out16 + (long)(off + gr) * 1024 + tn * 128 + wn + c8 * 8) = v;
  }
}

// ---------------- combine: out[t] = y[slot0] + y[slot1], 2 tokens/block ----------------
__global__ __launch_bounds__(256) void combine_kernel(
    const u16* __restrict__ y, const int* __restrict__ inv,
    float* __restrict__ out) {
  int t = blockIdx.x * 2 + (threadIdx.x >> 7);
  int tid = threadIdx.x & 127;
  int s0 = inv[2 * t], s1 = inv[2 * t + 1];
  uint4 a = *(const uint4*)(y + (long)s0 * 1024 + tid * 8);
  uint4 b = *(const uint4*)(y + (long)s1 * 1024 + tid * 8);
  float o[8];
  const u32* au = (const u32*)&a;
  const u32* bu = (const u32*)&b;
  #pragma unroll
  for (int i = 0; i < 4; i++) {
    union { u32 u; float f; } lo1, hi1, lo2, hi2;
    lo1.u = au[i] << 16;  hi1.u = au[i] & 0xFFFF0000u;
    lo2.u = bu[i] << 16;  hi2.u = bu[i] & 0xFFFF0000u;
    o[2 * i]     = lo1.f + lo2.f;
    o[2 * i + 1] = hi1.f + hi2.f;
  }
  float* op = out + (long)t * 1024 + tid * 8;
  *(float4*)op       = make_float4(o[0], o[1], o[2], o[3]);
  *(float4*)(op + 4) = make_float4(o[4], o[5], o[6], o[7]);
}

// ---------------- launch ----------------
extern "C" void kernel_launch(void* const* d_in, const int* in_sizes, int n_in,
                              void* d_out, int out_size, void* d_ws, size_t ws_size,
                              hipStream_t stream) {
  const float* x     = (const float*)d_in[0];
  const float* rw    = (const float*)d_in[1];
  const float* w1    = (const float*)d_in[2];
  const float* w2    = (const float*)d_in[3];
  const float* ebias = (const float*)d_in[4];
  float* out = (float*)d_out;

  char* ws = (char*)d_ws;
  // ws layout (bytes). y (GEMM2 output) OVERLAYS xb+w1t (dead after GEMM1).
  u16*    xb        = (u16*)(ws + 0);                 // 16,777,216
  u16*    w1t       = (u16*)(ws + 16777216);          // 16,777,216
  u16*    y         = (u16*)(ws + 0);                 // overlay, 33,554,432
  u16*    w2t       = (u16*)(ws + 33554432);          // 16,777,216
  u16*    h         = (u16*)(ws + 50331648);          // 16512 rows: 33,816,576
  int*    tok_list  = (int*)(ws + 84148224);          // 65,536
  float*  wt_list   = (float*)(ws + 84213760);        // 65,536
  int2*   sel       = (int2*)(ws + 84279296);         // 65,536
  float2* selw      = (float2*)(ws + 84344832);       // 65,536
  int*    inv       = (int*)(ws + 84705280);          // 65,536
  u32*    cnt       = (u32*)(ws + 84770816);          // counters block (512 B, memset 0)
  u32*    cursor    = cnt + 8;
  u32*    cnt_be    = cnt + 16;   // 32 entries [B][E]
  u32*    offs      = cnt + 48;
  float*  pe_sum    = (float*)(cnt + 56);             // 32 floats
  float*  z_sum     = (float*)(cnt + 88);             // 1 float

  hipMemsetAsync(cnt, 0, 512, stream);

  transpose_all<<<dim3(32, 32, 16), 256, 0, stream>>>(w1, w2, w1t, w2t);
  router_kernel<<<1024, 256, 0, stream>>>(x, rw, ebias, xb, sel, selw, cnt, cnt_be, pe_sum, z_sum);
  offsets_kernel<<<1, 64, 0, stream>>>(cnt, offs, cursor);
  build_finalize<<<32, 256, 0, stream>>>(sel, selw, cursor, tok_list, wt_list, inv,
                                         pe_sum, z_sum, cnt, cnt_be, out + 8388608);
  // worst case sum(ceil(cnt_e/128)) <= 135 row tiles; 8 col tiles; XCD-mapped
  moe_gemm<false><<<136 * 8, 256, 0, stream>>>(xb, w1t, h, tok_list, wt_list, cnt, offs);
  moe_gemm<true><<<136 * 8, 256, 0, stream>>>(h, w2t, y, tok_list, wt_list, cnt, offs);
  combine_kernel<<<4096, 256, 0, stream>>>(y, inv, out);
}